// Round 1
// 145.991 us; speedup vs baseline: 1.0200x; 1.0200x over previous
//
#include <hip/hip_runtime.h>
#include <math.h>

#define NW   12
#define DIM  4096
#define TPB  256

// complex multiply
__device__ __forceinline__ float2 cmulq(float2 a, float2 b) {
    return make_float2(fmaf(a.x, b.x, -a.y * b.y), fmaf(a.x, b.y, a.y * b.x));
}

// RY on register bit B (of the 4 k-bits). Pairs (i0, i0|1<<B), all indices compile-time.
template<int B>
__device__ __forceinline__ void ry_reg(float2* r, float c, float s) {
#pragma unroll
    for (int p = 0; p < 8; ++p) {
        const int i0 = ((p >> B) << (B + 1)) | (p & ((1 << B) - 1));
        const int i1 = i0 | (1 << B);
        const float2 a = r[i0], b = r[i1];
        r[i0].x = fmaf(-s, b.x, c * a.x);
        r[i0].y = fmaf(-s, b.y, c * a.y);
        r[i1].x = fmaf( s, a.x, c * b.x);
        r[i1].y = fmaf( s, a.y, c * b.y);
    }
}

// RY on lane bit B (0..5): partner via shfl_xor (conflict-free ds_swizzle/bpermute).
// lane bit=0 holds a: a' = c*a - s*b ;  lane bit=1 holds b: b' = c*b + s*a
template<int B>
__device__ __forceinline__ void ry_lane(float2* r, float c, float s, int tid) {
    const float ss = ((tid >> B) & 1) ? s : -s;
#pragma unroll
    for (int k = 0; k < 16; ++k) {
        const float px = __shfl_xor(r[k].x, 1 << B, 64);
        const float py = __shfl_xor(r[k].y, 1 << B, 64);
        r[k].x = fmaf(ss, px, c * r[k].x);
        r[k].y = fmaf(ss, py, c * r[k].y);
    }
}

__global__ __launch_bounds__(TPB, 4)
void qmnist_kernel(const float* __restrict__ x,  const float* __restrict__ W1,
                   const float* __restrict__ b1, const float* __restrict__ ryp,
                   const float* __restrict__ rzp, const float* __restrict__ W2,
                   const float* __restrict__ b2, float* __restrict__ out) {
    // Exactly 32 KiB LDS: the state buffer is only used for the two per-layer
    // round trips; all small arrays alias its front (state lives in registers,
    // so psi[] is dead whenever they are live; syncs order every transition).
    __shared__ float2 psi[DIM];
    float* smf  = (float*)psi;
    float* wred = smf;        // 48 floats
    float* encc = smf + 48;   // 12
    float* encs = smf + 60;   // 12
    float* zfin = smf + 72;   // 12

    const int tid  = threadIdx.x;
    const int blk  = blockIdx.x;
    const int lane = tid & 63;
    const int wave = tid >> 6;

    // ---------------- phase 0: feat = x[blk] @ W1^T + b1 -> encoding angles
    float acc[NW];
#pragma unroll
    for (int w = 0; w < NW; ++w) acc[w] = 0.f;
    if (tid < 196) {                      // 784 = 196 float4
        const float4 xv = ((const float4*)(x + (size_t)blk * 784))[tid];
#pragma unroll
        for (int w = 0; w < NW; ++w) {
            const float4 wv = ((const float4*)(W1 + w * 784))[tid];
            acc[w] = fmaf(xv.x, wv.x, fmaf(xv.y, wv.y, fmaf(xv.z, wv.z, xv.w * wv.w)));
        }
    }
#pragma unroll
    for (int w = 0; w < NW; ++w) {
        float v = acc[w];
        v += __shfl_down(v, 32);
        v += __shfl_down(v, 16);
        v += __shfl_down(v, 8);
        v += __shfl_down(v, 4);
        v += __shfl_down(v, 2);
        v += __shfl_down(v, 1);
        if (lane == 0) wred[wave * NW + w] = v;
    }
    __syncthreads();
    if (tid < NW) {
        float feat = wred[tid] + wred[NW + tid] + wred[2 * NW + tid] + wred[3 * NW + tid] + b1[tid];
        float a = tanhf(feat) * 3.14159265358979323846f;
        float h = 0.5f * a;
        encc[tid] = cosf(h);
        encs[tid] = sinf(h);
    }
    __syncthreads();

    // ---------------- init product state into REGISTERS.
    // amp index y = k*256 + tid; bit b of y <-> wire (11-b). bits 0..7 = tid, 8..11 = k.
    float hi = 1.f;
#pragma unroll
    for (int b = 0; b < 8; ++b)
        hi *= ((tid >> b) & 1) ? encs[11 - b] : encc[11 - b];
    float2 r[16];
#pragma unroll
    for (int k = 0; k < 16; ++k) {
        float f = hi;
        f *= (k & 1) ? encs[3] : encc[3];
        f *= (k & 2) ? encs[2] : encc[2];
        f *= (k & 4) ? encs[1] : encc[1];
        f *= (k & 8) ? encs[0] : encc[0];
        r[k] = make_float2(f, 0.f);
    }

    // ---------------- variational params.
    // Layer = (RY on all 12 wires) then (RZ on all 12 wires) then CNOT staircase.
    // All RZs compose into one diagonal phase e^{i*rz*(popcount(y)-6)}.
    const float ry = ryp[0], rz = rzp[0];
    const float c = cosf(0.5f * ry), s = sinf(0.5f * ry);
    const int pcT = __popc(tid);
    float2 q[5];                                   // q[j] = cis(rz*(popc(tid)+j-6)), j=popc(k)
#pragma unroll
    for (int j = 0; j < 5; ++j) {
        const float ang = rz * (float)(pcT + j - 6);
        q[j] = make_float2(cosf(ang), sinf(ang));
    }

    const int swb = (lane) | (((tid >> 6) & 3) << 8);   // swap-read base: bits 0-5 + tid6,7 -> 8,9

    for (int layer = 0; layer < 3; ++layer) {
        // RY on global bits 8..11 (register bits) — pure VALU
        ry_reg<0>(r, c, s); ry_reg<1>(r, c, s); ry_reg<2>(r, c, s); ry_reg<3>(r, c, s);
        // RY on global bits 0..5 (lane bits) — shfl butterflies
        ry_lane<0>(r, c, s, tid); ry_lane<1>(r, c, s, tid); ry_lane<2>(r, c, s, tid);
        ry_lane<3>(r, c, s, tid); ry_lane<4>(r, c, s, tid); ry_lane<5>(r, c, s, tid);

        // --- LDS round trip 1: swap bits (6,7)<->(8,9); both sides 64-consecutive -> conflict-free
        __syncthreads();                            // prior psi readers done
#pragma unroll
        for (int k = 0; k < 16; ++k) psi[k * TPB + tid] = r[k];
        __syncthreads();
#pragma unroll
        for (int k = 0; k < 16; ++k)
            r[k] = psi[swb | ((k & 3) << 6) | ((k >> 2) << 10)];

        // now global bits 6,7 sit at register bits 0,1 — gate them
        ry_reg<0>(r, c, s); ry_reg<1>(r, c, s);

        // fold of all 12 RZ gates: phase by popcount (bit-permutation invariant)
#pragma unroll
        for (int k = 0; k < 16; ++k)
            r[k] = cmulq(r[k], q[__popc(k)]);

        // --- LDS round trip 2: CNOT staircase new[y] = old[y ^ (y>>1)], fused with
        // the inverse bit-swap (sigma): lds[j] holds global sigma(j), so read sigma(g).
        __syncthreads();                            // swap-reads done before overwrite
#pragma unroll
        for (int k = 0; k < 16; ++k) psi[k * TPB + tid] = r[k];
        __syncthreads();
#pragma unroll
        for (int k = 0; k < 16; ++k) {
            const int y = k * TPB + tid;
            const int g = y ^ (y >> 1);
            const int a = (g & 0xC3F) | (((g >> 8) & 3) << 6) | (((g >> 6) & 3) << 8);
            r[k] = psi[a];                          // uniform base + lane bijection -> conflict-free
        }
    }
    __syncthreads();                                // all psi reads done before wred aliasing reuse

    // ---------------- measure <Z_w> from registers (state is back in L0 layout)
    float t_total = 0.f, s3 = 0.f, s2 = 0.f, s1 = 0.f, s0 = 0.f;
#pragma unroll
    for (int k = 0; k < 16; ++k) {
        const float pp = fmaf(r[k].x, r[k].x, r[k].y * r[k].y);
        t_total += pp;
        if (k & 1) s3 += pp;   // bit 8  -> wire 3
        if (k & 2) s2 += pp;   // bit 9  -> wire 2
        if (k & 4) s1 += pp;   // bit 10 -> wire 1
        if (k & 8) s0 += pp;   // bit 11 -> wire 0
    }
    float contrib[NW];
    contrib[3] = t_total - 2.f * s3;
    contrib[2] = t_total - 2.f * s2;
    contrib[1] = t_total - 2.f * s1;
    contrib[0] = t_total - 2.f * s0;
#pragma unroll
    for (int b = 0; b < 8; ++b) {
        const int w = 11 - b;                       // wires 11..4 from tid bits 0..7
        contrib[w] = ((tid >> b) & 1) ? -t_total : t_total;
    }
#pragma unroll
    for (int w = 0; w < NW; ++w) {
        float v = contrib[w];
        v += __shfl_down(v, 32);
        v += __shfl_down(v, 16);
        v += __shfl_down(v, 8);
        v += __shfl_down(v, 4);
        v += __shfl_down(v, 2);
        v += __shfl_down(v, 1);
        if (lane == 0) wred[wave * NW + w] = v;
    }
    __syncthreads();
    if (tid < NW)
        zfin[tid] = wred[tid] + wred[NW + tid] + wred[2 * NW + tid] + wred[3 * NW + tid];
    __syncthreads();

    // ---------------- head: out = z @ W2^T + b2
    if (tid < 10) {
        float o = b2[tid];
#pragma unroll
        for (int w = 0; w < NW; ++w)
            o = fmaf(zfin[w], W2[tid * NW + w], o);
        out[(size_t)blk * 10 + tid] = o;
    }
}

extern "C" void kernel_launch(void* const* d_in, const int* in_sizes, int n_in,
                              void* d_out, int out_size, void* d_ws, size_t ws_size,
                              hipStream_t stream) {
    const float* x   = (const float*)d_in[0];
    const float* W1  = (const float*)d_in[1];
    const float* b1  = (const float*)d_in[2];
    const float* ry  = (const float*)d_in[3];
    const float* rz  = (const float*)d_in[4];
    const float* W2  = (const float*)d_in[5];
    const float* b2  = (const float*)d_in[6];
    float* out = (float*)d_out;

    const int batch = in_sizes[0] / 784;   // 2048
    qmnist_kernel<<<batch, TPB, 0, stream>>>(x, W1, b1, ry, rz, W2, b2, out);
}